// Round 7
// baseline (75.959 us; speedup 1.0000x reference)
//
#include <hip/hip_runtime.h>
#include <cstdint>

#pragma clang fp contract(off)

typedef float v2f __attribute__((ext_vector_type(2)));

#define P_N 2048
#define F_N 8192
#define TPB 256
#define FPT 32
#define NT (F_N / FPT)
#define NC 44      // padded consts per face
#define QCAP 192

// ---- workspace layout ----
// [0, 1441792)        : face const table, f32 [F_N][NC]
// [1441792, 1449984)  : minub, u32 [P_N]
// [2097152, +16.8MB)  : LB codes, u8 [P_N][F_N] (viewed as u32 words)
#define WS_TAB_OFF    0
#define WS_MINUB_OFF  1441792
#define WS_LB_OFF     2097152
#define WS_NEEDED     (WS_LB_OFF + (size_t)P_N * F_N)

// =============== exact helpers (bit-identical to reference, proven R1-R6) ===============

__device__ __forceinline__ void face_setup(
    const float* __restrict__ vertices, const int* __restrict__ faces, int f,
    float* fd)
{
#pragma clang fp contract(off)
    int i0 = faces[3 * f + 0];
    int i1 = faces[3 * f + 1];
    int i2 = faces[3 * f + 2];
    float ax = vertices[3 * i0 + 0], ay = vertices[3 * i0 + 1], az = vertices[3 * i0 + 2];
    float bx = vertices[3 * i1 + 0], by = vertices[3 * i1 + 1], bz = vertices[3 * i1 + 2];
    float cx = vertices[3 * i2 + 0], cy = vertices[3 * i2 + 1], cz = vertices[3 * i2 + 2];
    float abx = bx - ax, aby = by - ay, abz = bz - az;
    float acx = cx - ax, acy = cy - ay, acz = cz - az;
    float daab = (ax * abx + ay * aby) + az * abz;
    float daac = (ax * acx + ay * acy) + az * acz;
    float dbab = (bx * abx + by * aby) + bz * abz;
    float dbac = (bx * acx + by * acy) + bz * acz;
    float dcab = (cx * abx + cy * aby) + cz * abz;
    float dcac = (cx * acx + cy * acy) + cz * acz;
    fd[0] = ax;  fd[1] = ay;  fd[2] = az;
    fd[3] = bx;  fd[4] = by;  fd[5] = bz;
    fd[6] = cx;  fd[7] = cy;  fd[8] = cz;
    fd[9] = abx; fd[10] = aby; fd[11] = abz;
    fd[12] = acx; fd[13] = acy; fd[14] = acz;
    fd[15] = daab; fd[16] = daac; fd[17] = dbab;
    fd[18] = dbac; fd[19] = dcab; fd[20] = dcac;
}

__device__ __forceinline__ void tri_eval_exact(
    float px, float py, float pz,
    const float* fd,
    float& w1o, float& w2o, float& w3o, float& disto)
{
#pragma clang fp contract(off)
    const float ax = fd[0], ay = fd[1], az = fd[2];
    const float bx = fd[3], by = fd[4], bz = fd[5];
    const float cx = fd[6], cy = fd[7], cz = fd[8];
    const float abx = fd[9], aby = fd[10], abz = fd[11];
    const float acx = fd[12], acy = fd[13], acz = fd[14];
    const float daab = fd[15], daac = fd[16], dbab = fd[17];
    const float dbac = fd[18], dcab = fd[19], dcac = fd[20];

    float pab = fmaf(pz, abz, fmaf(py, aby, px * abx));
    float pac = fmaf(pz, acz, fmaf(py, acy, px * acx));

    float d1 = pab - daab;
    float d2 = pac - daac;
    float d3 = pab - dbab;
    float d4 = pac - dbac;
    float d5 = pab - dcab;
    float d6 = pac - dcac;

    float vc = d1 * d4 - d3 * d2;
    float vb = d5 * d2 - d1 * d6;
    float va = d3 * d6 - d5 * d4;

    float denom = (va + vb) + vc;
    float dn = (denom == 0.0f) ? 1.0f : denom;
    float v7 = vb / dn;
    float w7 = vc / dn;
    float w1 = (1.0f - v7) - w7;
    float w2 = v7;
    float w3 = w7;

    float e63 = d4 - d3;
    float e65 = d5 - d6;
    float t6d = e63 + e65; t6d = (t6d == 0.0f) ? 1.0f : t6d;
    float t6 = e63 / t6d;
    if ((va <= 0.0f) & (e63 >= 0.0f) & (e65 >= 0.0f)) { w1 = 0.0f; w2 = 1.0f - t6; w3 = t6; }

    float t5d = d2 - d6; t5d = (t5d == 0.0f) ? 1.0f : t5d;
    float t5 = d2 / t5d;
    if ((vb <= 0.0f) & (d2 >= 0.0f) & (d6 <= 0.0f)) { w1 = 1.0f - t5; w2 = 0.0f; w3 = t5; }

    if ((d6 >= 0.0f) & (d5 <= d6)) { w1 = 0.0f; w2 = 0.0f; w3 = 1.0f; }

    float t3d = d1 - d3; t3d = (t3d == 0.0f) ? 1.0f : t3d;
    float t3 = d1 / t3d;
    if ((vc <= 0.0f) & (d1 >= 0.0f) & (d3 <= 0.0f)) { w1 = 1.0f - t3; w2 = t3; w3 = 0.0f; }

    if ((d3 >= 0.0f) & (d4 <= d3)) { w1 = 0.0f; w2 = 1.0f; w3 = 0.0f; }

    if ((d1 <= 0.0f) & (d2 <= 0.0f)) { w1 = 1.0f; w2 = 0.0f; w3 = 0.0f; }

    float cpx = (w1 * ax + w2 * bx) + w3 * cx;
    float cpy = (w1 * ay + w2 * by) + w3 * cy;
    float cpz = (w1 * az + w2 * bz) + w3 * cz;
    float dx = px - cpx, dy = py - cpy, dz = pz - cpz;
    float dist = (dx * dx + dy * dy) + dz * dz;

    w1o = w1; w2o = w2; w3o = w3; disto = dist;
}

// =============== k_prep: per-face constant table + minub init ===============
// tab indices: 0..20 exact fd; 21 kcs 22 kct 23 kcc; 24 kbs 25 kbt 26 kbc;
// 27 kas 28 kat 29 kac; 30 nx 31 ny 32 nz 33 mnd; 34 iab 35 iac 36 ibc 37 inn;
// 38 abab 39 acac; 40 marg; 41..43 pad.

__global__ __launch_bounds__(64) void k_prep(
    const float* __restrict__ vertices, const int* __restrict__ faces,
    float* __restrict__ tab, unsigned* __restrict__ minub)
{
#pragma clang fp contract(off)
    int f = blockIdx.x * 64 + threadIdx.x;
    if (f < F_N) {
        float td[NC];
        face_setup(vertices, faces, f, td);
        float ax = td[0], ay = td[1], az = td[2];
        float bx = td[3], by = td[4], bz = td[5];
        float cx = td[6], cy = td[7], cz = td[8];
        float abx = td[9], aby = td[10], abz = td[11];
        float acx = td[12], acy = td[13], acz = td[14];
        float A = td[15], B = td[16], C = td[17], D = td[18], E = td[19], F = td[20];
        td[21] = B - D; td[22] = C - A; td[23] = A * D - C * B;
        td[24] = F - B; td[25] = A - E; td[26] = E * B - A * F;
        td[27] = D - F; td[28] = E - C; td[29] = C * F - E * D;
        float nx = aby * acz - abz * acy;
        float ny = abz * acx - abx * acz;
        float nz = abx * acy - aby * acx;
        float nn = (nx * nx + ny * ny) + nz * nz;
        float abab = (abx * abx + aby * aby) + abz * abz;
        float acac = (acx * acx + acy * acy) + acz * acz;
        float bcx = cx - bx, bcy = cy - by, bcz = cz - bz;
        float bcbc = (bcx * bcx + bcy * bcy) + bcz * bcz;
        float inv_ab = abab > 0.0f ? 1.0f / abab : 0.0f;
        float inv_ac = acac > 0.0f ? 1.0f / acac : 0.0f;
        float inv_bc = bcbc > 0.0f ? 1.0f / bcbc : 0.0f;
        float inv_nn = nn >= 1e-2f ? 1.0f / nn : 0.0f;
        float L2 = abab + acac;
        float infl = 1e-4f * L2 * sqrtf(L2) * inv_nn;
        float marg = 3e-4f + infl * infl;
        bool bad = (nn < 1e-2f) | (abab < 1e-3f) | (acac < 1e-3f) | (bcbc < 1e-3f) | (marg > 0.25f);
        if (bad) marg = 1e30f;
        td[30] = nx; td[31] = ny; td[32] = nz;
        td[33] = -((nx * ax + ny * ay) + nz * az);
        td[34] = inv_ab; td[35] = inv_ac; td[36] = inv_bc; td[37] = inv_nn;
        td[38] = abab; td[39] = acac; td[40] = marg;
        td[41] = 0.0f; td[42] = 0.0f; td[43] = 0.0f;
#pragma unroll
        for (int k = 0; k < NC; k += 4)
            *(float4*)&tab[f * NC + k] = *(float4*)&td[k];
    }
    if (f < P_N) minub[f] = 0x7f7f7f7fu;  // large positive float
}

// =============== k_screen: bounds + u8 LB codes ===============

__device__ __forceinline__ void screen_face2(
    float d1, float d2, float d3, float d4, float d5, float d6,
    float va, float vb, float vc, float e63, float e65,
    float pa2, float pb2, float pc2,
    float sub3, float sub5, float sub6, float subI,
    float marg,
    float& ubmin, int& codeout)
{
    bool m1 = (d1 <= 0.0f) & (d2 <= 0.0f);
    bool m2 = (d3 >= 0.0f) & (d4 <= d3);
    bool m3 = (vc <= 0.0f) & (d1 >= 0.0f) & (d3 <= 0.0f);
    bool m4 = (d6 >= 0.0f) & (d5 <= d6);
    bool m5 = (vb <= 0.0f) & (d2 >= 0.0f) & (d6 <= 0.0f);
    bool m6 = (va <= 0.0f) & (e63 >= 0.0f) & (e65 >= 0.0f);
    float screen = m1 ? pa2 : m2 ? pb2 : m3 ? sub3 : m4 ? pc2 : m5 ? sub5 : m6 ? sub6 : subI;
    screen = fmaxf(screen, 0.0f);
    bool bad = marg > 0.25f;
    if (!bad) ubmin = fminf(ubmin, screen + marg);
    float lb = bad ? 0.0f : fmaxf(fmaf(0.99f, screen, -marg), 0.0f);
    int code = (int)(__float_as_uint(lb) >> 20) - 896;  // monotone, rounds down
    codeout = code < 0 ? 0 : (code > 255 ? 255 : code);
}

__global__ __launch_bounds__(TPB) void k_screen(
    const float* __restrict__ points,
    const float* __restrict__ tab,
    unsigned* __restrict__ minub,
    unsigned* __restrict__ lbw)
{
#pragma clang fp contract(off)
    __shared__ float sq[NC][FPT];

    const int pblk = blockIdx.x, fblk = blockIdx.y, t = threadIdx.x;
    const int fbase = fblk * FPT;
    {
        int q0 = t >> 5, slot = t & 31;
        for (int qq = q0; qq < NC; qq += 8)
            sq[qq][slot] = tab[(fbase + slot) * NC + qq];
    }
    __syncthreads();

    const int p = pblk * TPB + t;
    const float px = points[3 * p + 0];
    const float py = points[3 * p + 1];
    const float pz = points[3 * p + 2];
    const v2f pxv = {px, px}, pyv = {py, py}, pzv = {pz, pz};
    const v2f n2v = {-2.0f, -2.0f};

    float ubmin = 3e38f;
    unsigned cw[FPT / 4];
#pragma unroll
    for (int k = 0; k < FPT / 4; ++k) cw[k] = 0;

#pragma unroll 2
    for (int jp = 0; jp < FPT / 2; ++jp) {
        const int j = jp * 2;
#define L2D(k) (*(const v2f*)&sq[k][j])
        v2f s = __builtin_elementwise_fma(pzv, L2D(11),
                    __builtin_elementwise_fma(pyv, L2D(10), pxv * L2D(9)));
        v2f tt = __builtin_elementwise_fma(pzv, L2D(14),
                    __builtin_elementwise_fma(pyv, L2D(13), pxv * L2D(12)));

        v2f d1 = s - L2D(15);
        v2f d2 = tt - L2D(16);
        v2f d3 = s - L2D(17);
        v2f d4 = tt - L2D(18);
        v2f d5 = s - L2D(19);
        v2f d6 = tt - L2D(20);

        v2f vc = __builtin_elementwise_fma(s, L2D(21),
                    __builtin_elementwise_fma(tt, L2D(22), L2D(23)));
        v2f vb = __builtin_elementwise_fma(s, L2D(24),
                    __builtin_elementwise_fma(tt, L2D(25), L2D(26)));
        v2f va = __builtin_elementwise_fma(s, L2D(27),
                    __builtin_elementwise_fma(tt, L2D(28), L2D(29)));

        v2f e63 = d4 - d3;
        v2f e65 = d5 - d6;

        v2f nd = __builtin_elementwise_fma(L2D(32), pzv,
                    __builtin_elementwise_fma(L2D(31), pyv,
                        __builtin_elementwise_fma(L2D(30), pxv, L2D(33))));

        v2f dax = pxv - L2D(0);
        v2f day = pyv - L2D(1);
        v2f daz = pzv - L2D(2);
        v2f pa2 = __builtin_elementwise_fma(daz, daz,
                     __builtin_elementwise_fma(day, day, dax * dax));
        v2f pb2 = __builtin_elementwise_fma(n2v, d1, pa2) + L2D(38);
        v2f pc2 = __builtin_elementwise_fma(n2v, d2, pa2) + L2D(39);

        v2f sub3 = __builtin_elementwise_fma(-(d1 * L2D(34)), d1, pa2);
        v2f sub5 = __builtin_elementwise_fma(-(d2 * L2D(35)), d2, pa2);
        v2f sub6 = __builtin_elementwise_fma(-(e63 * L2D(36)), e63, pb2);
        v2f subI = (nd * L2D(37)) * nd;

        v2f mg = L2D(40);
#undef L2D

        int c0, c1;
        screen_face2(d1.x, d2.x, d3.x, d4.x, d5.x, d6.x, va.x, vb.x, vc.x,
                     e63.x, e65.x, pa2.x, pb2.x, pc2.x,
                     sub3.x, sub5.x, sub6.x, subI.x, mg.x, ubmin, c0);
        screen_face2(d1.y, d2.y, d3.y, d4.y, d5.y, d6.y, va.y, vb.y, vc.y,
                     e63.y, e65.y, pa2.y, pb2.y, pc2.y,
                     sub3.y, sub5.y, sub6.y, subI.y, mg.y, ubmin, c1);

        cw[jp >> 1] |= ((unsigned)c0 << (8 * ((2 * jp) & 3)))
                     | ((unsigned)c1 << (8 * ((2 * jp + 1) & 3)));
    }

    atomicMin(&minub[p], __float_as_uint(ubmin));

    unsigned* dst = &lbw[p * (F_N / 4) + fblk * (FPT / 4)];
    *(uint4*)&dst[0] = make_uint4(cw[0], cw[1], cw[2], cw[3]);
    *(uint4*)&dst[4] = make_uint4(cw[4], cw[5], cw[6], cw[7]);
}

// =============== k_exact: wave-per-point candidate compaction + exact eval ===============

__global__ __launch_bounds__(TPB) void k_exact(
    const float* __restrict__ points,
    const float* __restrict__ tab,
    const unsigned* __restrict__ minub,
    const unsigned* __restrict__ lbw,
    float* __restrict__ out)
{
    __shared__ unsigned short qbuf[4][QCAP];
    __shared__ int qcnt[4];

    const int w = threadIdx.x >> 6;
    const int lane = threadIdx.x & 63;
    const int p = blockIdx.x * 4 + w;

    if (lane == 0) qcnt[w] = 0;
    __syncthreads();

    const float px = points[3 * p + 0];
    const float py = points[3 * p + 1];
    const float pz = points[3 * p + 2];
    int thr = (int)(minub[p] >> 20) - 896;
    thr = thr < 0 ? 0 : (thr > 255 ? 255 : thr);

    const unsigned* mylb = &lbw[p * (F_N / 4)];
    for (int it = 0; it < F_N / 256; ++it) {  // 32 iterations
        unsigned word = mylb[it * 64 + lane];
#pragma unroll
        for (int b = 0; b < 4; ++b) {
            int code = (word >> (8 * b)) & 255;
            if (code <= thr) {
                int slot = atomicAdd(&qcnt[w], 1);
                if (slot < QCAP) qbuf[w][slot] = (unsigned short)((it * 64 + lane) * 4 + b);
            }
        }
    }
    __syncthreads();
    const int n = qcnt[w];

    unsigned long long bestk = ~0ull;
    float bw1 = 0.0f, bw2 = 0.0f, bw3 = 0.0f;

    auto eval1 = [&](int f) {
        float fdl[21];
#pragma unroll
        for (int k = 0; k < 20; k += 4)
            *(float4*)&fdl[k] = *(const float4*)&tab[f * NC + k];
        fdl[20] = tab[f * NC + 20];
        float w1, w2, w3, dist;
        tri_eval_exact(px, py, pz, fdl, w1, w2, w3, dist);
        unsigned db = __float_as_uint(dist);
        if (dist != dist) db = 0u;  // NaN -> -inf (numpy argmin: first NaN wins)
        unsigned long long key = ((unsigned long long)db << 32) | (unsigned)f;
        if (key < bestk) { bestk = key; bw1 = w1; bw2 = w2; bw3 = w3; }
    };

    if (n > QCAP) {
        for (int f = lane; f < F_N; f += 64) eval1(f);   // overflow fallback (p~0)
    } else {
        for (int r = lane; r < n; r += 64) eval1((int)qbuf[w][r]);
    }

    const unsigned long long myk = bestk;
    unsigned long long red = bestk;
#pragma unroll
    for (int off = 32; off > 0; off >>= 1) {
        unsigned long long o = __shfl_xor(red, off, 64);
        red = o < red ? o : red;
    }
    if (myk == red) {  // unique winner: keys contain distinct face ids
        int f = (int)(red & 0xffffffffull);
        out[p] = (float)f;
        out[P_N + p] = bw1;
        out[2 * P_N + p] = bw2;
        out[3 * P_N + p] = bw3;
    }
}

// =============== fallback: proven R5 full scan (only if ws too small) ===============

__device__ __forceinline__ void region_w(
    float d1, float d2, float d3, float d4, float d5, float d6,
    float va, float vb, float vc, float e63, float e65, float denom,
    float& w1, float& w2, float& w3)
{
#pragma clang fp contract(off)
    bool m1 = (d1 <= 0.0f) & (d2 <= 0.0f);
    bool m2 = (d3 >= 0.0f) & (d4 <= d3);
    bool m3 = (vc <= 0.0f) & (d1 >= 0.0f) & (d3 <= 0.0f);
    bool m4 = (d6 >= 0.0f) & (d5 <= d6);
    bool m5 = (vb <= 0.0f) & (d2 >= 0.0f) & (d6 <= 0.0f);
    bool m6 = (va <= 0.0f) & (e63 >= 0.0f) & (e65 >= 0.0f);
    bool anym = m1 | m2 | m3 | m4 | m5 | m6;

    float n1  = m1 ? 0.0f : m2 ? 0.0f : m3 ? d1        : m4 ? 0.0f : m5 ? d2        : m6 ? e63         : vb;
    float ds1 = m1 ? 1.0f : m2 ? 1.0f : m3 ? (d1 - d3) : m4 ? 1.0f : m5 ? (d2 - d6) : m6 ? (e63 + e65) : denom;
    ds1 = (ds1 == 0.0f) ? 1.0f : ds1;
    float n2  = anym ? 0.0f : vc;
    float ds2 = anym ? 1.0f : ((denom == 0.0f) ? 1.0f : denom);

    float q1 = n1 / ds1;
    float q2 = n2 / ds2;
    float u = (1.0f - q1) - q2;

    w1 = m1 ? 1.0f : m2 ? 0.0f : m3 ? u    : m4 ? 0.0f : m5 ? u    : m6 ? 0.0f : u;
    w2 = m1 ? 0.0f : m2 ? 1.0f : m3 ? q1   : m4 ? 0.0f : m5 ? 0.0f : m6 ? u    : q1;
    w3 = m1 ? 0.0f : m2 ? 0.0f : m3 ? 0.0f : m4 ? 1.0f : m5 ? q1   : m6 ? q1   : q2;
}

__global__ __launch_bounds__(TPB) void k_scan_full(
    const float* __restrict__ points,
    const float* __restrict__ vertices,
    const int* __restrict__ faces,
    unsigned long long* __restrict__ best)
{
#pragma clang fp contract(off)
    __shared__ float sq[21][FPT];
    const int pblk = blockIdx.x, fblk = blockIdx.y, t = threadIdx.x;
    if (t < FPT) {
        float fd[21];
        face_setup(vertices, faces, fblk * FPT + t, fd);
#pragma unroll
        for (int k = 0; k < 21; ++k) sq[k][t] = fd[k];
    }
    __syncthreads();

    const int p = pblk * TPB + t;
    const float px = points[3 * p], py = points[3 * p + 1], pz = points[3 * p + 2];
    const v2f pxv = {px, px}, pyv = {py, py}, pzv = {pz, pz};

    unsigned int bestdb = 0xffffffffu;
    int bestf = 0;
    const int fbase = fblk * FPT;

#pragma unroll 2
    for (int j = 0; j < FPT; j += 2) {
#define LD2(q) (*(const v2f*)&sq[q][j])
        v2f axv = LD2(0),  ayv = LD2(1),  azv = LD2(2);
        v2f bxv = LD2(3),  byv = LD2(4),  bzv = LD2(5);
        v2f cxv = LD2(6),  cyv = LD2(7),  czv = LD2(8);
        v2f abxv = LD2(9),  abyv = LD2(10), abzv = LD2(11);
        v2f acxv = LD2(12), acyv = LD2(13), aczv = LD2(14);
        v2f daabv = LD2(15), daacv = LD2(16), dbabv = LD2(17);
        v2f dbacv = LD2(18), dcabv = LD2(19), dcacv = LD2(20);
#undef LD2
        v2f pab = __builtin_elementwise_fma(pzv, abzv,
                    __builtin_elementwise_fma(pyv, abyv, pxv * abxv));
        v2f pac = __builtin_elementwise_fma(pzv, aczv,
                    __builtin_elementwise_fma(pyv, acyv, pxv * acxv));
        v2f d1 = pab - daabv, d2 = pac - daacv, d3 = pab - dbabv;
        v2f d4 = pac - dbacv, d5 = pab - dcabv, d6 = pac - dcacv;
        v2f vcv = d1 * d4 - d3 * d2;
        v2f vbv = d5 * d2 - d1 * d6;
        v2f vav = d3 * d6 - d5 * d4;
        v2f e63 = d4 - d3, e65 = d5 - d6;
        v2f denom = (vav + vbv) + vcv;

        float w1a, w2a, w3a, w1b, w2b, w3b;
        region_w(d1.x, d2.x, d3.x, d4.x, d5.x, d6.x,
                 vav.x, vbv.x, vcv.x, e63.x, e65.x, denom.x, w1a, w2a, w3a);
        region_w(d1.y, d2.y, d3.y, d4.y, d5.y, d6.y,
                 vav.y, vbv.y, vcv.y, e63.y, e65.y, denom.y, w1b, w2b, w3b);

        v2f w1v = {w1a, w1b}, w2v = {w2a, w2b}, w3v = {w3a, w3b};
        v2f cpx = (w1v * axv + w2v * bxv) + w3v * cxv;
        v2f cpy = (w1v * ayv + w2v * byv) + w3v * cyv;
        v2f cpz = (w1v * azv + w2v * bzv) + w3v * czv;
        v2f dx = pxv - cpx, dy = pyv - cpy, dz = pzv - cpz;
        v2f dist = (dx * dx + dy * dy) + dz * dz;

        float da = dist.x, db = dist.y;
        unsigned ua = __float_as_uint(da), ub = __float_as_uint(db);
        if (da != da) ua = 0u;
        if (db != db) ub = 0u;
        if (ua < bestdb) { bestdb = ua; bestf = fbase + j; }
        if (ub < bestdb) { bestdb = ub; bestf = fbase + j + 1; }
    }

    unsigned long long key =
        ((unsigned long long)bestdb << 32) | (unsigned int)bestf;
    atomicMin(&best[p], key);
}

__global__ __launch_bounds__(TPB) void k_final(
    const float* __restrict__ points,
    const float* __restrict__ vertices,
    const int* __restrict__ faces,
    const unsigned long long* __restrict__ best,
    float* __restrict__ out)
{
    const int p = blockIdx.x * TPB + threadIdx.x;
    if (p >= P_N) return;
    int f = (int)(best[p] & 0xffffffffull);
    float fd[21];
    face_setup(vertices, faces, f, fd);
    float w1, w2, w3, dist;
    tri_eval_exact(points[3 * p], points[3 * p + 1], points[3 * p + 2], fd, w1, w2, w3, dist);
    out[p] = (float)f;
    out[P_N + p] = w1;
    out[2 * P_N + p] = w2;
    out[3 * P_N + p] = w3;
}

extern "C" void kernel_launch(void* const* d_in, const int* in_sizes, int n_in,
                              void* d_out, int out_size, void* d_ws, size_t ws_size,
                              hipStream_t stream)
{
    const float* points = (const float*)d_in[0];
    const float* vertices = (const float*)d_in[1];
    const int* faces = (const int*)d_in[2];
    float* out = (float*)d_out;
    char* ws = (char*)d_ws;

    if (ws_size >= WS_NEEDED) {
        float* tab = (float*)(ws + WS_TAB_OFF);
        unsigned* minub = (unsigned*)(ws + WS_MINUB_OFF);
        unsigned* lbw = (unsigned*)(ws + WS_LB_OFF);

        k_prep<<<F_N / 64, 64, 0, stream>>>(vertices, faces, tab, minub);
        k_screen<<<dim3(P_N / TPB, NT), TPB, 0, stream>>>(points, tab, minub, lbw);
        k_exact<<<P_N / 4, TPB, 0, stream>>>(points, tab, minub, lbw, out);
    } else {
        unsigned long long* best = (unsigned long long*)ws;
        hipMemsetAsync(best, 0xFF, P_N * sizeof(unsigned long long), stream);
        k_scan_full<<<dim3(P_N / TPB, NT), TPB, 0, stream>>>(points, vertices, faces, best);
        k_final<<<(P_N + TPB - 1) / TPB, TPB, 0, stream>>>(points, vertices, faces, best, out);
    }
}

// Round 8
// 66.309 us; speedup vs baseline: 1.1455x; 1.1455x over previous
//
#include <hip/hip_runtime.h>
#include <cstdint>

#pragma clang fp contract(off)

typedef float v2f __attribute__((ext_vector_type(2)));

#define P_N 2048
#define F_N 8192
#define TPB 256
#define FPT 32
#define NT (F_N / FPT)
#define TW 28   // floats per face in const table: 21 exact + nx,ny,nz,mnd,inn + pad

// ---- workspace layout ----
// [0, F_N*TW*4)        : face const table
// then minub u32[P_N], best u64[P_N]
#define WS_TAB_BYTES   (F_N * TW * 4)
#define WS_MINUB_OFF   WS_TAB_BYTES
#define WS_BEST_OFF    (WS_TAB_BYTES + P_N * 4)
#define WS_NEEDED      (WS_BEST_OFF + P_N * 8)

// =============== exact helpers (bit-identical to reference, proven R1-R7) ===============

__device__ __forceinline__ void face_setup(
    const float* __restrict__ vertices, const int* __restrict__ faces, int f,
    float* fd)
{
#pragma clang fp contract(off)
    int i0 = faces[3 * f + 0];
    int i1 = faces[3 * f + 1];
    int i2 = faces[3 * f + 2];
    float ax = vertices[3 * i0 + 0], ay = vertices[3 * i0 + 1], az = vertices[3 * i0 + 2];
    float bx = vertices[3 * i1 + 0], by = vertices[3 * i1 + 1], bz = vertices[3 * i1 + 2];
    float cx = vertices[3 * i2 + 0], cy = vertices[3 * i2 + 1], cz = vertices[3 * i2 + 2];
    float abx = bx - ax, aby = by - ay, abz = bz - az;
    float acx = cx - ax, acy = cy - ay, acz = cz - az;
    float daab = (ax * abx + ay * aby) + az * abz;
    float daac = (ax * acx + ay * acy) + az * acz;
    float dbab = (bx * abx + by * aby) + bz * abz;
    float dbac = (bx * acx + by * acy) + bz * acz;
    float dcab = (cx * abx + cy * aby) + cz * abz;
    float dcac = (cx * acx + cy * acy) + cz * acz;
    fd[0] = ax;  fd[1] = ay;  fd[2] = az;
    fd[3] = bx;  fd[4] = by;  fd[5] = bz;
    fd[6] = cx;  fd[7] = cy;  fd[8] = cz;
    fd[9] = abx; fd[10] = aby; fd[11] = abz;
    fd[12] = acx; fd[13] = acy; fd[14] = acz;
    fd[15] = daab; fd[16] = daac; fd[17] = dbab;
    fd[18] = dbac; fd[19] = dcab; fd[20] = dcac;
}

__device__ __forceinline__ void tri_eval_exact(
    float px, float py, float pz,
    const float* __restrict__ fd,
    float& w1o, float& w2o, float& w3o, float& disto)
{
#pragma clang fp contract(off)
    const float ax = fd[0], ay = fd[1], az = fd[2];
    const float bx = fd[3], by = fd[4], bz = fd[5];
    const float cx = fd[6], cy = fd[7], cz = fd[8];
    const float abx = fd[9], aby = fd[10], abz = fd[11];
    const float acx = fd[12], acy = fd[13], acz = fd[14];
    const float daab = fd[15], daac = fd[16], dbab = fd[17];
    const float dbac = fd[18], dcab = fd[19], dcac = fd[20];

    float pab = fmaf(pz, abz, fmaf(py, aby, px * abx));
    float pac = fmaf(pz, acz, fmaf(py, acy, px * acx));

    float d1 = pab - daab;
    float d2 = pac - daac;
    float d3 = pab - dbab;
    float d4 = pac - dbac;
    float d5 = pab - dcab;
    float d6 = pac - dcac;

    float vc = d1 * d4 - d3 * d2;
    float vb = d5 * d2 - d1 * d6;
    float va = d3 * d6 - d5 * d4;

    float denom = (va + vb) + vc;
    float dn = (denom == 0.0f) ? 1.0f : denom;
    float v7 = vb / dn;
    float w7 = vc / dn;
    float w1 = (1.0f - v7) - w7;
    float w2 = v7;
    float w3 = w7;

    float e63 = d4 - d3;
    float e65 = d5 - d6;
    float t6d = e63 + e65; t6d = (t6d == 0.0f) ? 1.0f : t6d;
    float t6 = e63 / t6d;
    if ((va <= 0.0f) & (e63 >= 0.0f) & (e65 >= 0.0f)) { w1 = 0.0f; w2 = 1.0f - t6; w3 = t6; }

    float t5d = d2 - d6; t5d = (t5d == 0.0f) ? 1.0f : t5d;
    float t5 = d2 / t5d;
    if ((vb <= 0.0f) & (d2 >= 0.0f) & (d6 <= 0.0f)) { w1 = 1.0f - t5; w2 = 0.0f; w3 = t5; }

    if ((d6 >= 0.0f) & (d5 <= d6)) { w1 = 0.0f; w2 = 0.0f; w3 = 1.0f; }

    float t3d = d1 - d3; t3d = (t3d == 0.0f) ? 1.0f : t3d;
    float t3 = d1 / t3d;
    if ((vc <= 0.0f) & (d1 >= 0.0f) & (d3 <= 0.0f)) { w1 = 1.0f - t3; w2 = t3; w3 = 0.0f; }

    if ((d3 >= 0.0f) & (d4 <= d3)) { w1 = 0.0f; w2 = 1.0f; w3 = 0.0f; }

    if ((d1 <= 0.0f) & (d2 <= 0.0f)) { w1 = 1.0f; w2 = 0.0f; w3 = 0.0f; }

    float cpx = (w1 * ax + w2 * bx) + w3 * cx;
    float cpy = (w1 * ay + w2 * by) + w3 * cy;
    float cpz = (w1 * az + w2 * bz) + w3 * cz;
    float dx = px - cpx, dy = py - cpy, dz = pz - cpz;
    float dist = (dx * dx + dy * dy) + dz * dz;

    w1o = w1; w2o = w2; w3o = w3; disto = dist;
}

// =============== k_prep: const table + init ===============

__global__ __launch_bounds__(TPB) void k_prep(
    const float* __restrict__ vertices, const int* __restrict__ faces,
    float* __restrict__ tab, unsigned* __restrict__ minub,
    unsigned long long* __restrict__ best)
{
#pragma clang fp contract(off)
    int f = blockIdx.x * TPB + threadIdx.x;
    if (f < F_N) {
        float td[TW];
        face_setup(vertices, faces, f, td);
        float ax = td[0], ay = td[1], az = td[2];
        float abx = td[9], aby = td[10], abz = td[11];
        float acx = td[12], acy = td[13], acz = td[14];
        float nx = aby * acz - abz * acy;
        float ny = abz * acx - abx * acz;
        float nz = abx * acy - aby * acx;
        float nn = (nx * nx + ny * ny) + nz * nz;
        float abab = (abx * abx + aby * aby) + abz * abz;
        float acac = (acx * acx + acy * acy) + acz * acz;
        float L2v = abab + acac;
        bool bad = !(nn >= 1e-2f * L2v) || (nn < 1e-20f);
        td[21] = nx; td[22] = ny; td[23] = nz;
        td[24] = -((nx * ax + ny * ay) + nz * az);   // mnd
        td[25] = bad ? -1.0f : 1.0f / nn;            // inn (<0 marks bad)
        td[26] = 0.0f; td[27] = 0.0f;
#pragma unroll
        for (int k = 0; k < TW; k += 4)
            *(float4*)&tab[f * TW + k] = *(float4*)&td[k];
    }
    if (f < P_N) {
        minub[f] = 0x7f7f7f7fu;   // large positive float bits
        best[f] = ~0ull;
    }
}

// =============== k_bound: per-tile heuristic pick + exact UB ===============

__global__ __launch_bounds__(TPB) void k_bound(
    const float* __restrict__ points,
    const float* __restrict__ tab,
    unsigned* __restrict__ minub)
{
#pragma clang fp contract(off)
    const int pblk = blockIdx.x, fblk = blockIdx.y, t = threadIdx.x;
    const int fbase = fblk * FPT;
    const int p = pblk * TPB + t;
    const float px = points[3 * p + 0];
    const float py = points[3 * p + 1];
    const float pz = points[3 * p + 2];

    float bestv = 1e30f;
    int bestj = fbase;

#pragma unroll 4
    for (int j = 0; j < FPT; ++j) {
        const float* __restrict__ tf = tab + (size_t)(fbase + j) * TW;
        float nx = tf[21], ny = tf[22], nz = tf[23], mnd = tf[24], inn = tf[25];
        float nd = fmaf(nz, pz, fmaf(ny, py, fmaf(nx, px, mnd)));
        float p2 = (nd * nd) * inn;
        bool better = (p2 >= 0.0f) & (p2 < bestv);   // excludes bad (<0) and NaN
        bestv = better ? p2 : bestv;
        bestj = better ? (fbase + j) : bestj;
    }

    // exact-eval the chosen face: its d_ref is a SOUND upper bound on min dist
    float fd[21];
#pragma unroll
    for (int k = 0; k < 20; k += 4)
        *(float4*)&fd[k] = *(const float4*)&tab[(size_t)bestj * TW + k];
    fd[20] = tab[(size_t)bestj * TW + 20];
    float w1, w2, w3, dist;
    tri_eval_exact(px, py, pz, fd, w1, w2, w3, dist);
    if (!(dist != dist)) atomicMin(&minub[p], __float_as_uint(dist));  // dist >= 0
}

// =============== k_scan2: LB-pruned exact scan ===============

__global__ __launch_bounds__(TPB) void k_scan2(
    const float* __restrict__ points,
    const float* __restrict__ tab,
    const unsigned* __restrict__ minub,
    unsigned long long* __restrict__ best)
{
#pragma clang fp contract(off)
    const int pblk = blockIdx.x, fblk = blockIdx.y, t = threadIdx.x;
    const int fbase = fblk * FPT;
    const int p = pblk * TPB + t;
    const float px = points[3 * p + 0];
    const float py = points[3 * p + 1];
    const float pz = points[3 * p + 2];
    const float thr = __uint_as_float(minub[p]);

    unsigned bestdb = 0xffffffffu;
    int bestf = 0;

#pragma unroll 2
    for (int j = 0; j < FPT; ++j) {
        const float* __restrict__ tf = tab + (size_t)(fbase + j) * TW;
        float nx = tf[21], ny = tf[22], nz = tf[23], mnd = tf[24], inn = tf[25];
        float nd = fmaf(nz, pz, fmaf(ny, py, fmaf(nx, px, mnd)));
        float p2 = (nd * nd) * inn;                         // <0 for bad faces
        float lb = fmaxf(fmaf(p2, 0.97f, -1e-6f), 0.0f);    // sound LB (NaN -> 0)
        if (__any(lb <= thr)) {
            float w1, w2, w3, dist;
            tri_eval_exact(px, py, pz, tf, w1, w2, w3, dist);
            unsigned db = __float_as_uint(dist);
            if (dist != dist) db = 0u;   // NaN -> -inf (numpy argmin: first NaN wins)
            if (db < bestdb) { bestdb = db; bestf = fbase + j; }
        }
    }

    unsigned long long key =
        ((unsigned long long)bestdb << 32) | (unsigned)bestf;
    atomicMin(&best[p], key);
}

// =============== k_final ===============

__global__ __launch_bounds__(TPB) void k_final(
    const float* __restrict__ points,
    const float* __restrict__ vertices,
    const int* __restrict__ faces,
    const unsigned long long* __restrict__ best,
    float* __restrict__ out)
{
    const int p = blockIdx.x * TPB + threadIdx.x;
    if (p >= P_N) return;
    int f = (int)(best[p] & 0x1fffull);  // mask guards OOB in pathological case
    float fd[21];
    face_setup(vertices, faces, f, fd);
    float w1, w2, w3, dist;
    tri_eval_exact(points[3 * p], points[3 * p + 1], points[3 * p + 2],
                   fd, w1, w2, w3, dist);
    out[p] = (float)f;
    out[P_N + p] = w1;
    out[2 * P_N + p] = w2;
    out[3 * P_N + p] = w3;
}

// =============== fallback: proven R5 full scan (tiny ws only) ===============

__device__ __forceinline__ void region_w(
    float d1, float d2, float d3, float d4, float d5, float d6,
    float va, float vb, float vc, float e63, float e65, float denom,
    float& w1, float& w2, float& w3)
{
#pragma clang fp contract(off)
    bool m1 = (d1 <= 0.0f) & (d2 <= 0.0f);
    bool m2 = (d3 >= 0.0f) & (d4 <= d3);
    bool m3 = (vc <= 0.0f) & (d1 >= 0.0f) & (d3 <= 0.0f);
    bool m4 = (d6 >= 0.0f) & (d5 <= d6);
    bool m5 = (vb <= 0.0f) & (d2 >= 0.0f) & (d6 <= 0.0f);
    bool m6 = (va <= 0.0f) & (e63 >= 0.0f) & (e65 >= 0.0f);
    bool anym = m1 | m2 | m3 | m4 | m5 | m6;

    float n1  = m1 ? 0.0f : m2 ? 0.0f : m3 ? d1        : m4 ? 0.0f : m5 ? d2        : m6 ? e63         : vb;
    float ds1 = m1 ? 1.0f : m2 ? 1.0f : m3 ? (d1 - d3) : m4 ? 1.0f : m5 ? (d2 - d6) : m6 ? (e63 + e65) : denom;
    ds1 = (ds1 == 0.0f) ? 1.0f : ds1;
    float n2  = anym ? 0.0f : vc;
    float ds2 = anym ? 1.0f : ((denom == 0.0f) ? 1.0f : denom);

    float q1 = n1 / ds1;
    float q2 = n2 / ds2;
    float u = (1.0f - q1) - q2;

    w1 = m1 ? 1.0f : m2 ? 0.0f : m3 ? u    : m4 ? 0.0f : m5 ? u    : m6 ? 0.0f : u;
    w2 = m1 ? 0.0f : m2 ? 1.0f : m3 ? q1   : m4 ? 0.0f : m5 ? 0.0f : m6 ? u    : q1;
    w3 = m1 ? 0.0f : m2 ? 0.0f : m3 ? 0.0f : m4 ? 1.0f : m5 ? q1   : m6 ? q1   : q2;
}

__global__ __launch_bounds__(TPB) void k_scan_full(
    const float* __restrict__ points,
    const float* __restrict__ vertices,
    const int* __restrict__ faces,
    unsigned long long* __restrict__ best)
{
#pragma clang fp contract(off)
    __shared__ float sq[21][FPT];
    const int pblk = blockIdx.x, fblk = blockIdx.y, t = threadIdx.x;
    if (t < FPT) {
        float fd[21];
        face_setup(vertices, faces, fblk * FPT + t, fd);
#pragma unroll
        for (int k = 0; k < 21; ++k) sq[k][t] = fd[k];
    }
    __syncthreads();

    const int p = pblk * TPB + t;
    const float px = points[3 * p], py = points[3 * p + 1], pz = points[3 * p + 2];
    const v2f pxv = {px, px}, pyv = {py, py}, pzv = {pz, pz};

    unsigned int bestdb = 0xffffffffu;
    int bestf = 0;
    const int fbase = fblk * FPT;

#pragma unroll 2
    for (int j = 0; j < FPT; j += 2) {
#define LD2(q) (*(const v2f*)&sq[q][j])
        v2f axv = LD2(0),  ayv = LD2(1),  azv = LD2(2);
        v2f bxv = LD2(3),  byv = LD2(4),  bzv = LD2(5);
        v2f cxv = LD2(6),  cyv = LD2(7),  czv = LD2(8);
        v2f abxv = LD2(9),  abyv = LD2(10), abzv = LD2(11);
        v2f acxv = LD2(12), acyv = LD2(13), aczv = LD2(14);
        v2f daabv = LD2(15), daacv = LD2(16), dbabv = LD2(17);
        v2f dbacv = LD2(18), dcabv = LD2(19), dcacv = LD2(20);
#undef LD2
        v2f pab = __builtin_elementwise_fma(pzv, abzv,
                    __builtin_elementwise_fma(pyv, abyv, pxv * abxv));
        v2f pac = __builtin_elementwise_fma(pzv, aczv,
                    __builtin_elementwise_fma(pyv, acyv, pxv * acxv));
        v2f d1 = pab - daabv, d2 = pac - daacv, d3 = pab - dbabv;
        v2f d4 = pac - dbacv, d5 = pab - dcabv, d6 = pac - dcacv;
        v2f vcv = d1 * d4 - d3 * d2;
        v2f vbv = d5 * d2 - d1 * d6;
        v2f vav = d3 * d6 - d5 * d4;
        v2f e63 = d4 - d3, e65 = d5 - d6;
        v2f denom = (vav + vbv) + vcv;

        float w1a, w2a, w3a, w1b, w2b, w3b;
        region_w(d1.x, d2.x, d3.x, d4.x, d5.x, d6.x,
                 vav.x, vbv.x, vcv.x, e63.x, e65.x, denom.x, w1a, w2a, w3a);
        region_w(d1.y, d2.y, d3.y, d4.y, d5.y, d6.y,
                 vav.y, vbv.y, vcv.y, e63.y, e65.y, denom.y, w1b, w2b, w3b);

        v2f w1v = {w1a, w1b}, w2v = {w2a, w2b}, w3v = {w3a, w3b};
        v2f cpx = (w1v * axv + w2v * bxv) + w3v * cxv;
        v2f cpy = (w1v * ayv + w2v * byv) + w3v * cyv;
        v2f cpz = (w1v * azv + w2v * bzv) + w3v * czv;
        v2f dx = pxv - cpx, dy = pyv - cpy, dz = pzv - cpz;
        v2f dist = (dx * dx + dy * dy) + dz * dz;

        float da = dist.x, db = dist.y;
        unsigned ua = __float_as_uint(da), ub = __float_as_uint(db);
        if (da != da) ua = 0u;
        if (db != db) ub = 0u;
        if (ua < bestdb) { bestdb = ua; bestf = fbase + j; }
        if (ub < bestdb) { bestdb = ub; bestf = fbase + j + 1; }
    }

    unsigned long long key =
        ((unsigned long long)bestdb << 32) | (unsigned int)bestf;
    atomicMin(&best[p], key);
}

extern "C" void kernel_launch(void* const* d_in, const int* in_sizes, int n_in,
                              void* d_out, int out_size, void* d_ws, size_t ws_size,
                              hipStream_t stream)
{
    const float* points = (const float*)d_in[0];
    const float* vertices = (const float*)d_in[1];
    const int* faces = (const int*)d_in[2];
    float* out = (float*)d_out;
    char* ws = (char*)d_ws;

    if (ws_size >= WS_NEEDED) {
        float* tab = (float*)ws;
        unsigned* minub = (unsigned*)(ws + WS_MINUB_OFF);
        unsigned long long* best = (unsigned long long*)(ws + WS_BEST_OFF);

        k_prep<<<F_N / TPB, TPB, 0, stream>>>(vertices, faces, tab, minub, best);
        k_bound<<<dim3(P_N / TPB, NT), TPB, 0, stream>>>(points, tab, minub);
        k_scan2<<<dim3(P_N / TPB, NT), TPB, 0, stream>>>(points, tab, minub, best);
        k_final<<<(P_N + TPB - 1) / TPB, TPB, 0, stream>>>(points, vertices, faces, best, out);
    } else {
        unsigned long long* best = (unsigned long long*)ws;
        hipMemsetAsync(best, 0xFF, P_N * sizeof(unsigned long long), stream);
        k_scan_full<<<dim3(P_N / TPB, NT), TPB, 0, stream>>>(points, vertices, faces, best);
        k_final<<<(P_N + TPB - 1) / TPB, TPB, 0, stream>>>(points, vertices, faces, best, out);
    }
}